// Round 1
// baseline (112.776 us; speedup 1.0000x reference)
//
#include <hip/hip_runtime.h>

// MultiStep n-step return bookkeeping. B=2048, T=512, D=64, N=3, GAMMA=0.99.
// Inputs: done(int32 bool), mask(int32 bool), reward(f32), next_obs(f32).
// Outputs (all f32, concatenated): gamma_masked[B,T,1], steps[B,T,1],
// nonterminal[B,T,1], partial_return[B,T,1], next_obs_out[B,T,D], done_out[B,T,1].

constexpr int   NSTEP = 3;
constexpr int   Bb    = 2048;
constexpr int   Tt    = 512;
constexpr int   Dd    = 64;
constexpr float GAM   = 0.99f;
constexpr long long BT = (long long)Bb * Tt;

__global__ __launch_bounds__(256) void multistep_kernel(
    const int* __restrict__ done, const int* __restrict__ mask,
    const float* __restrict__ reward, const float* __restrict__ next_obs,
    float* __restrict__ out)
{
    const int b   = blockIdx.x;
    const int tid = threadIdx.x;

    __shared__ float g_s[Tt + NSTEP];
    __shared__ float r_s[Tt + NSTEP];
    __shared__ unsigned char done_s[Tt];
    __shared__ unsigned char mask_s[Tt];
    __shared__ float last_obs[Dd];
    __shared__ int s_total;
    __shared__ int s_first;
    __shared__ int s_cnt;
    __shared__ int s_pos[32];

    const int*   drow = done   + (long long)b * Tt;
    const int*   mrow = mask   + (long long)b * Tt;
    const float* rrow = reward + (long long)b * Tt;
    const float* orow = next_obs + (long long)b * Tt * Dd;

    if (tid == 0) { s_total = 0; s_first = Tt; s_cnt = 0; }
    __syncthreads();

    int local_sum = 0;
    for (int t = tid; t < Tt; t += 256) {
        int dv = (drow[t] != 0);
        int mv = (mrow[t] != 0);
        done_s[t] = (unsigned char)dv;
        mask_s[t] = (unsigned char)mv;
        g_s[t] = mv ? GAM : 1.0f;
        r_s[t] = rrow[t];
        local_sum += dv;
    }
    if (tid < NSTEP) { g_s[Tt + tid] = 1.0f; r_s[Tt + tid] = 0.0f; }
    if (local_sum) atomicAdd(&s_total, local_sum);
    __syncthreads();

    const int total = s_total;
    // terminal[t] = done[t], with last column forced if (done[T-1] | total!=1)
    for (int t = tid; t < Tt; t += 256) {
        int term = done_s[t] || (t == Tt - 1 && total != 1);
        if (term) {
            atomicMin(&s_first, t);
            int pos = atomicAdd(&s_cnt, 1);
            if (pos < 32) s_pos[pos] = t;
        }
    }
    __syncthreads();
    const int   p         = s_first;          // first terminal
    const int   cnt       = s_cnt < 32 ? s_cnt : 32;
    const float last_done = (float)total;     // sum(terminal * done) == sum(done)

    // last_obs[d] = sum over terminal positions of next_obs[t, d]
    if (tid < Dd) {
        float acc = 0.0f;
        for (int i = 0; i < cnt; ++i) acc += orow[(long long)s_pos[i] * Dd + tid];
        last_obs[tid] = acc;
    }
    __syncthreads();

    float* out_gm  = out;
    float* out_st  = out + BT;
    float* out_nt  = out + 2 * BT;
    float* out_pr  = out + 3 * BT;
    float* out_obs = out + 4 * BT;
    float* out_do  = out + 4 * BT + (long long)Dd * BT;

    const long long rowoff = (long long)b * Tt;

    // scalar-per-t outputs
    for (int t = tid; t < Tt; t += 256) {
        float gm = g_s[t] * g_s[t + 1] * g_s[t + 2] * g_s[t + 3];
        int steps = p - t + 1;
        steps = steps < 0 ? 0 : (steps > NSTEP + 1 ? NSTEP + 1 : steps);
        float nonterm = (t <= p) ? 1.0f : 0.0f;
        float pr = r_s[t] + 0.99f * r_s[t + 1] + 0.9801f * r_s[t + 2]
                 + 0.970299f * r_s[t + 3];
        int   m    = mask_s[t];
        float dval = ((t + NSTEP < Tt) ? (float)done_s[t + NSTEP] : 0.0f)
                   + ((t + NSTEP > p) ? last_done : 0.0f);
        out_gm[rowoff + t] = gm;
        out_st[rowoff + t] = (float)steps;
        out_nt[rowoff + t] = nonterm;
        out_pr[rowoff + t] = pr;
        out_do[rowoff + t] = (m && dval > 0.5f) ? 1.0f : 0.0f;
    }

    // next_obs_out: out[t,d] = mask[t] ? ((t+N<T ? obs[t+N,d] : 0) + (t+N>p ? last_obs[d] : 0)) : 0
    const int dlane = (tid & 15) * 4;   // 16 lanes x float4 cover D=64
    const int trow  = tid >> 4;         // 16 rows per iteration
    for (int t0 = 0; t0 < Tt; t0 += 16) {
        int t = t0 + trow;
        int s = t + NSTEP;
        float4 v = make_float4(0.0f, 0.0f, 0.0f, 0.0f);
        if (mask_s[t]) {
            if (s < Tt) v = *(const float4*)(orow + (long long)s * Dd + dlane);
            if (s > p) {
                v.x += last_obs[dlane];
                v.y += last_obs[dlane + 1];
                v.z += last_obs[dlane + 2];
                v.w += last_obs[dlane + 3];
            }
        }
        *(float4*)(out_obs + (rowoff + t) * Dd + dlane) = v;
    }
}

extern "C" void kernel_launch(void* const* d_in, const int* in_sizes, int n_in,
                              void* d_out, int out_size, void* d_ws, size_t ws_size,
                              hipStream_t stream) {
    const int*   done     = (const int*)d_in[0];
    const int*   mask     = (const int*)d_in[1];
    const float* reward   = (const float*)d_in[2];
    const float* next_obs = (const float*)d_in[3];
    float*       out      = (float*)d_out;

    multistep_kernel<<<Bb, 256, 0, stream>>>(done, mask, reward, next_obs, out);
}

// Round 2
// 109.817 us; speedup vs baseline: 1.0269x; 1.0269x over previous
//
#include <hip/hip_runtime.h>

// MultiStep n-step return bookkeeping. B=2048, T=512, D=64, N=3, GAMMA=0.99.
// Inputs: done(int32 bool), mask(int32 bool), reward(f32), next_obs(f32).
// Outputs (all f32, concat): gamma_masked[B,T,1], steps[B,T,1], nonterminal[B,T,1],
// partial_return[B,T,1], next_obs_out[B,T,D], done_out[B,T,1].
//
// Two-kernel split: K1 = per-row bookkeeping + scalar outputs + params to ws
// (small traffic, latency-bound phases). K2 = pure streaming next_obs pass
// (~450 MB of the ~484 MB total), no atomics, nontemporal load/store.

constexpr int   NSTEP = 3;
constexpr int   Bb    = 2048;
constexpr int   Tt    = 512;
constexpr int   Dd    = 64;
constexpr float GAM   = 0.99f;
constexpr long long BT = (long long)Bb * Tt;

typedef float f4v __attribute__((ext_vector_type(4)));

// ws layout: int p[B] @0 ; float last_done[B] @B ; float last_obs[B][64] @2B
constexpr size_t WS_NEEDED = (size_t)(2 * Bb + Bb * Dd) * 4;

__global__ __launch_bounds__(256) void k1_bookkeep(
    const int* __restrict__ done, const int* __restrict__ mask,
    const float* __restrict__ reward, const float* __restrict__ next_obs,
    float* __restrict__ out, int* __restrict__ ws_p,
    float* __restrict__ ws_ld, float* __restrict__ ws_obs)
{
    const int b   = blockIdx.x;
    const int tid = threadIdx.x;

    __shared__ float g_s[Tt + NSTEP];
    __shared__ float r_s[Tt + NSTEP];
    __shared__ unsigned char done_s[Tt];
    __shared__ unsigned char mask_s[Tt];
    __shared__ float lo[Dd];
    __shared__ int s_total, s_first, s_cnt;
    __shared__ int s_pos[32];

    if (tid == 0) { s_total = 0; s_first = Tt; s_cnt = 0; }
    __syncthreads();

    const int4*   d4 = (const int4*)(done + (long long)b * Tt);
    const int4*   m4 = (const int4*)(mask + (long long)b * Tt);
    const float4* r4 = (const float4*)(reward + (long long)b * Tt);
    const float*  orow = next_obs + (long long)b * Tt * Dd;

    if (tid < Tt / 4) {
        int4   dv = d4[tid];
        int4   mv = m4[tid];
        float4 rv = r4[tid];
        int base = 4 * tid;
        int c = (dv.x != 0) + (dv.y != 0) + (dv.z != 0) + (dv.w != 0);
        done_s[base]     = dv.x != 0; done_s[base + 1] = dv.y != 0;
        done_s[base + 2] = dv.z != 0; done_s[base + 3] = dv.w != 0;
        mask_s[base]     = mv.x != 0; mask_s[base + 1] = mv.y != 0;
        mask_s[base + 2] = mv.z != 0; mask_s[base + 3] = mv.w != 0;
        g_s[base]     = mv.x ? GAM : 1.0f; g_s[base + 1] = mv.y ? GAM : 1.0f;
        g_s[base + 2] = mv.z ? GAM : 1.0f; g_s[base + 3] = mv.w ? GAM : 1.0f;
        r_s[base] = rv.x; r_s[base + 1] = rv.y;
        r_s[base + 2] = rv.z; r_s[base + 3] = rv.w;
        if (c) atomicAdd(&s_total, c);
    }
    if (tid < NSTEP) { g_s[Tt + tid] = 1.0f; r_s[Tt + tid] = 0.0f; }
    __syncthreads();

    const int total = s_total;
    for (int t = tid; t < Tt; t += 256) {
        int term = done_s[t] || (t == Tt - 1 && total != 1);
        if (term) {
            atomicMin(&s_first, t);
            int pos = atomicAdd(&s_cnt, 1);
            if (pos < 32) s_pos[pos] = t;
        }
    }
    __syncthreads();
    const int   p         = s_first;
    const int   cnt       = s_cnt < 32 ? s_cnt : 32;
    const float last_done = (float)total;   // sum(terminal*done) == sum(done)

    if (tid < Dd) {
        float acc = 0.0f;
        for (int i = 0; i < cnt; ++i) acc += orow[(long long)s_pos[i] * Dd + tid];
        lo[tid] = acc;
    }
    __syncthreads();

    if (tid == 0) { ws_p[b] = p; ws_ld[b] = last_done; }
    if (tid < Dd / 4)
        *(f4v*)(ws_obs + (long long)b * Dd + tid * 4) = *(const f4v*)(lo + tid * 4);

    float* out_gm = out;
    float* out_st = out + BT;
    float* out_nt = out + 2 * BT;
    float* out_pr = out + 3 * BT;
    float* out_do = out + 4 * BT + (long long)Dd * BT;
    const long long rowoff = (long long)b * Tt;

    for (int t = tid; t < Tt; t += 256) {
        float gm = g_s[t] * g_s[t + 1] * g_s[t + 2] * g_s[t + 3];
        int steps = p - t + 1;
        steps = steps < 0 ? 0 : (steps > NSTEP + 1 ? NSTEP + 1 : steps);
        float nonterm = (t <= p) ? 1.0f : 0.0f;
        float pr = r_s[t] + 0.99f * r_s[t + 1] + 0.9801f * r_s[t + 2]
                 + 0.970299f * r_s[t + 3];
        float dval = ((t + NSTEP < Tt) ? (float)done_s[t + NSTEP] : 0.0f)
                   + ((t + NSTEP > p) ? last_done : 0.0f);
        out_gm[rowoff + t] = gm;
        out_st[rowoff + t] = (float)steps;
        out_nt[rowoff + t] = nonterm;
        out_pr[rowoff + t] = pr;
        out_do[rowoff + t] = (mask_s[t] && dval > 0.5f) ? 1.0f : 0.0f;
    }
}

__global__ __launch_bounds__(256) void k2_stream(
    const int* __restrict__ mask, const float* __restrict__ next_obs,
    float* __restrict__ out_obs, const int* __restrict__ ws_p,
    const float* __restrict__ ws_obs)
{
    const int b   = blockIdx.x;
    const int tid = threadIdx.x;

    __shared__ unsigned char mask_s[Tt];
    __shared__ float lo[Dd];
    __shared__ int sp;

    const int4* m4 = (const int4*)(mask + (long long)b * Tt);
    if (tid < Tt / 4) {
        int4 mv = m4[tid];
        int base = 4 * tid;
        mask_s[base]     = mv.x != 0; mask_s[base + 1] = mv.y != 0;
        mask_s[base + 2] = mv.z != 0; mask_s[base + 3] = mv.w != 0;
    }
    if (tid < Dd / 4)
        *(f4v*)(lo + tid * 4) = *(const f4v*)(ws_obs + (long long)b * Dd + tid * 4);
    if (tid == 0) sp = ws_p[b];
    __syncthreads();

    const int p = sp;
    const float* orow     = next_obs + (long long)b * Tt * Dd;
    float*       orow_out = out_obs  + (long long)b * Tt * Dd;

    const int dlane = (tid & 15) * 4;   // 16 lanes x float4 cover D=64
    const int trow  = tid >> 4;         // 16 rows per iteration
    const f4v l4 = *(const f4v*)(lo + dlane);

#pragma unroll 4
    for (int t0 = 0; t0 < Tt; t0 += 16) {
        int t = t0 + trow;
        int s = t + NSTEP;
        f4v v = {0.0f, 0.0f, 0.0f, 0.0f};
        if (mask_s[t]) {
            if (s < Tt)
                v = __builtin_nontemporal_load(
                        (const f4v*)(orow + (long long)s * Dd + dlane));
            if (s > p) v += l4;
        }
        __builtin_nontemporal_store(v, (f4v*)(orow_out + (long long)t * Dd + dlane));
    }
}

// Fallback single kernel (used only if ws_size is too small for params).
__global__ __launch_bounds__(256) void multistep_single(
    const int* __restrict__ done, const int* __restrict__ mask,
    const float* __restrict__ reward, const float* __restrict__ next_obs,
    float* __restrict__ out)
{
    const int b   = blockIdx.x;
    const int tid = threadIdx.x;

    __shared__ float g_s[Tt + NSTEP];
    __shared__ float r_s[Tt + NSTEP];
    __shared__ unsigned char done_s[Tt];
    __shared__ unsigned char mask_s[Tt];
    __shared__ float last_obs[Dd];
    __shared__ int s_total, s_first, s_cnt;
    __shared__ int s_pos[32];

    const int*   drow = done   + (long long)b * Tt;
    const int*   mrow = mask   + (long long)b * Tt;
    const float* rrow = reward + (long long)b * Tt;
    const float* orow = next_obs + (long long)b * Tt * Dd;

    if (tid == 0) { s_total = 0; s_first = Tt; s_cnt = 0; }
    __syncthreads();

    int local_sum = 0;
    for (int t = tid; t < Tt; t += 256) {
        int dv = (drow[t] != 0);
        int mv = (mrow[t] != 0);
        done_s[t] = (unsigned char)dv;
        mask_s[t] = (unsigned char)mv;
        g_s[t] = mv ? GAM : 1.0f;
        r_s[t] = rrow[t];
        local_sum += dv;
    }
    if (tid < NSTEP) { g_s[Tt + tid] = 1.0f; r_s[Tt + tid] = 0.0f; }
    if (local_sum) atomicAdd(&s_total, local_sum);
    __syncthreads();

    const int total = s_total;
    for (int t = tid; t < Tt; t += 256) {
        int term = done_s[t] || (t == Tt - 1 && total != 1);
        if (term) {
            atomicMin(&s_first, t);
            int pos = atomicAdd(&s_cnt, 1);
            if (pos < 32) s_pos[pos] = t;
        }
    }
    __syncthreads();
    const int   p         = s_first;
    const int   cnt       = s_cnt < 32 ? s_cnt : 32;
    const float last_done = (float)total;

    if (tid < Dd) {
        float acc = 0.0f;
        for (int i = 0; i < cnt; ++i) acc += orow[(long long)s_pos[i] * Dd + tid];
        last_obs[tid] = acc;
    }
    __syncthreads();

    float* out_gm  = out;
    float* out_st  = out + BT;
    float* out_nt  = out + 2 * BT;
    float* out_pr  = out + 3 * BT;
    float* out_obs = out + 4 * BT;
    float* out_do  = out + 4 * BT + (long long)Dd * BT;
    const long long rowoff = (long long)b * Tt;

    for (int t = tid; t < Tt; t += 256) {
        float gm = g_s[t] * g_s[t + 1] * g_s[t + 2] * g_s[t + 3];
        int steps = p - t + 1;
        steps = steps < 0 ? 0 : (steps > NSTEP + 1 ? NSTEP + 1 : steps);
        float nonterm = (t <= p) ? 1.0f : 0.0f;
        float pr = r_s[t] + 0.99f * r_s[t + 1] + 0.9801f * r_s[t + 2]
                 + 0.970299f * r_s[t + 3];
        float dval = ((t + NSTEP < Tt) ? (float)done_s[t + NSTEP] : 0.0f)
                   + ((t + NSTEP > p) ? last_done : 0.0f);
        out_gm[rowoff + t] = gm;
        out_st[rowoff + t] = (float)steps;
        out_nt[rowoff + t] = nonterm;
        out_pr[rowoff + t] = pr;
        out_do[rowoff + t] = (mask_s[t] && dval > 0.5f) ? 1.0f : 0.0f;
    }

    const int dlane = (tid & 15) * 4;
    const int trow  = tid >> 4;
    for (int t0 = 0; t0 < Tt; t0 += 16) {
        int t = t0 + trow;
        int s = t + NSTEP;
        float4 v = make_float4(0.0f, 0.0f, 0.0f, 0.0f);
        if (mask_s[t]) {
            if (s < Tt) v = *(const float4*)(orow + (long long)s * Dd + dlane);
            if (s > p) {
                v.x += last_obs[dlane];
                v.y += last_obs[dlane + 1];
                v.z += last_obs[dlane + 2];
                v.w += last_obs[dlane + 3];
            }
        }
        *(float4*)(out_obs + (rowoff + t) * Dd + dlane) = v;
    }
}

extern "C" void kernel_launch(void* const* d_in, const int* in_sizes, int n_in,
                              void* d_out, int out_size, void* d_ws, size_t ws_size,
                              hipStream_t stream) {
    const int*   done     = (const int*)d_in[0];
    const int*   mask     = (const int*)d_in[1];
    const float* reward   = (const float*)d_in[2];
    const float* next_obs = (const float*)d_in[3];
    float*       out      = (float*)d_out;

    if (ws_size >= WS_NEEDED) {
        int*   ws_p   = (int*)d_ws;
        float* ws_ld  = (float*)d_ws + Bb;
        float* ws_obs = (float*)d_ws + 2 * Bb;
        float* out_obs = out + 4 * BT;
        k1_bookkeep<<<Bb, 256, 0, stream>>>(done, mask, reward, next_obs, out,
                                            ws_p, ws_ld, ws_obs);
        k2_stream<<<Bb, 256, 0, stream>>>(mask, next_obs, out_obs, ws_p, ws_obs);
    } else {
        multistep_single<<<Bb, 256, 0, stream>>>(done, mask, reward, next_obs, out);
    }
}

// Round 3
// 84.215 us; speedup vs baseline: 1.3391x; 1.3040x over previous
//
#include <hip/hip_runtime.h>

// MultiStep n-step return bookkeeping. B=2048, T=512, D=64, N=3, GAMMA=0.99.
// Inputs: done(int32 bool), mask(int32 bool), reward(f32), next_obs(f32).
// Outputs (all f32, concat): gamma_masked[B,T,1], steps[B,T,1], nonterminal[B,T,1],
// partial_return[B,T,1], next_obs_out[B,T,D], done_out[B,T,1].
//
// Single fused kernel, one block per row, ONE __syncthreads:
//  - stage done/mask/reward in LDS (vectorized int4/float4)
//  - each wave independently computes first-terminal p, total, terminal bitmap
//    via 8 __ballot's (no atomics), gathers last_obs itself (lane = d, coalesced),
//    redistributes to float4 layout via __shfl, then streams its 128-row quarter.

constexpr int   NSTEP = 3;
constexpr int   Bb    = 2048;
constexpr int   Tt    = 512;
constexpr int   Dd    = 64;
constexpr float GAM   = 0.99f;
constexpr long long BT = (long long)Bb * Tt;

typedef float f4v __attribute__((ext_vector_type(4)));

__global__ __launch_bounds__(256) void multistep_fused(
    const int* __restrict__ done, const int* __restrict__ mask,
    const float* __restrict__ reward, const float* __restrict__ next_obs,
    float* __restrict__ out)
{
    const int b    = blockIdx.x;
    const int tid  = threadIdx.x;
    const int lane = tid & 63;
    const int wid  = tid >> 6;

    __shared__ unsigned char done_s[Tt];
    __shared__ unsigned char mask_s[Tt];
    __shared__ float g_s[Tt + NSTEP];
    __shared__ float r_s[Tt + NSTEP];

    const int4*   d4 = (const int4*)(done + (long long)b * Tt);
    const int4*   m4 = (const int4*)(mask + (long long)b * Tt);
    const float4* r4 = (const float4*)(reward + (long long)b * Tt);
    const float*  orow = next_obs + (long long)b * Tt * Dd;

    if (tid < Tt / 4) {
        int4   dv = d4[tid];
        float4 rv = r4[tid];
        int base = 4 * tid;
        done_s[base]     = dv.x != 0; done_s[base + 1] = dv.y != 0;
        done_s[base + 2] = dv.z != 0; done_s[base + 3] = dv.w != 0;
        r_s[base] = rv.x; r_s[base + 1] = rv.y;
        r_s[base + 2] = rv.z; r_s[base + 3] = rv.w;
    } else {
        int tt = tid - Tt / 4;
        int4 mv = m4[tt];
        int base = 4 * tt;
        mask_s[base]     = mv.x != 0; mask_s[base + 1] = mv.y != 0;
        mask_s[base + 2] = mv.z != 0; mask_s[base + 3] = mv.w != 0;
        g_s[base]     = mv.x ? GAM : 1.0f; g_s[base + 1] = mv.y ? GAM : 1.0f;
        g_s[base + 2] = mv.z ? GAM : 1.0f; g_s[base + 3] = mv.w ? GAM : 1.0f;
    }
    if (tid < NSTEP) { g_s[Tt + tid] = 1.0f; r_s[Tt + tid] = 0.0f; }
    __syncthreads();

    // ---- per-wave bookkeeping: ballots over done bits (no atomics, no syncs) ----
    int total = 0;
    int p = Tt;
    unsigned long long bits[Tt / 64];
#pragma unroll
    for (int g = 0; g < Tt / 64; ++g) {
        int v = done_s[g * 64 + lane];
        unsigned long long bm = __ballot(v != 0);
        bits[g] = bm;
        total += __popcll(bm);
        if (p == Tt && bm) p = g * 64 + __builtin_ctzll(bm);
    }
    // forced terminal at T-1 when total != 1 and it's not already done
    if (total != 1 && !done_s[Tt - 1]) {
        bits[Tt / 64 - 1] |= 0x8000000000000000ull;
        if (p == Tt) p = Tt - 1;
    }
    const float last_done = (float)total;  // sum(terminal*done) == sum(done)

    // gather last_obs[d] for d = lane (uniform bit loop, coalesced 256B loads)
    float acc = 0.0f;
#pragma unroll
    for (int g = 0; g < Tt / 64; ++g) {
        unsigned long long bm = bits[g];
        while (bm) {
            int t = g * 64 + __builtin_ctzll(bm);
            bm &= bm - 1;
            acc += orow[(long long)t * Dd + lane];
        }
    }

    float* out_gm  = out;
    float* out_st  = out + BT;
    float* out_nt  = out + 2 * BT;
    float* out_pr  = out + 3 * BT;
    float* out_obs = out + 4 * BT;
    float* out_do  = out + 4 * BT + (long long)Dd * BT;
    const long long rowoff = (long long)b * Tt;

    // ---- scalar-per-t outputs: wave w owns rows [w*128, w*128+128) ----
    const int tbase = wid * 128;
#pragma unroll
    for (int k = 0; k < 2; ++k) {
        int t = tbase + k * 64 + lane;
        float gm = g_s[t] * g_s[t + 1] * g_s[t + 2] * g_s[t + 3];
        int steps = p - t + 1;
        steps = steps < 0 ? 0 : (steps > NSTEP + 1 ? NSTEP + 1 : steps);
        float nonterm = (t <= p) ? 1.0f : 0.0f;
        float pr = r_s[t] + 0.99f * r_s[t + 1] + 0.9801f * r_s[t + 2]
                 + 0.970299f * r_s[t + 3];
        float dval = ((t + NSTEP < Tt) ? (float)done_s[t + NSTEP] : 0.0f)
                   + ((t + NSTEP > p) ? last_done : 0.0f);
        out_gm[rowoff + t] = gm;
        out_st[rowoff + t] = (float)steps;
        out_nt[rowoff + t] = nonterm;
        out_pr[rowoff + t] = pr;
        out_do[rowoff + t] = (mask_s[t] && dval > 0.5f) ? 1.0f : 0.0f;
    }

    // ---- next_obs streaming: wave w owns rows [w*128, w*128+128) ----
    const int dlane = (lane & 15) * 4;  // 16 lanes x float4 cover D=64
    const int trow  = lane >> 4;        // 4 rows per wave-iteration
    f4v l4;
    l4.x = __shfl(acc, dlane, 64);
    l4.y = __shfl(acc, dlane + 1, 64);
    l4.z = __shfl(acc, dlane + 2, 64);
    l4.w = __shfl(acc, dlane + 3, 64);

    float* orow_out = out_obs + rowoff * Dd;
#pragma unroll 4
    for (int t0 = 0; t0 < 128; t0 += 4) {
        int t = tbase + t0 + trow;
        int s = t + NSTEP;
        f4v v = {0.0f, 0.0f, 0.0f, 0.0f};
        if (mask_s[t]) {
            if (s < Tt) v = *(const f4v*)(orow + (long long)s * Dd + dlane);
            if (s > p) v += l4;
        }
        __builtin_nontemporal_store(v, (f4v*)(orow_out + (long long)t * Dd + dlane));
    }
}

extern "C" void kernel_launch(void* const* d_in, const int* in_sizes, int n_in,
                              void* d_out, int out_size, void* d_ws, size_t ws_size,
                              hipStream_t stream) {
    const int*   done     = (const int*)d_in[0];
    const int*   mask     = (const int*)d_in[1];
    const float* reward   = (const float*)d_in[2];
    const float* next_obs = (const float*)d_in[3];
    float*       out      = (float*)d_out;

    multistep_fused<<<Bb, 256, 0, stream>>>(done, mask, reward, next_obs, out);
}